// Round 1
// baseline (179.124 us; speedup 1.0000x reference)
//
#include <hip/hip_runtime.h>

// GripperRegionNetwork: B=512, G=8192, C=6, REGION_NUM=1024
//
// Inputs (d_in order):
//  0: group_points  f32 (B,G,6)
//  1: group_index   i32 (B,G)
//  2: grasp         f32 (B,7)
//  3: widths  f32 scalar (1)
//  4: height  f32 scalar (1)
//  5: depths  f32 scalar (1)
//  6: region_num int scalar (1)   -- derived on host from out_size instead
//
// Outputs concatenated in d_out (all written as f32; int values exact in f32):
//  0: gripper_pc            (B,RN,6)
//  1: gripper_pc_index      (B,RN)
//  2: gripper_pc_index_inall(B,RN)
//  3: true_mask             (B)

__device__ __forceinline__ float fm(float a, float b) { return __fmul_rn(a, b); }
__device__ __forceinline__ float fa(float a, float b) { return __fadd_rn(a, b); }
__device__ __forceinline__ float fs(float a, float b) { return __fsub_rn(a, b); }
__device__ __forceinline__ float fd(float a, float b) { return __fdiv_rn(a, b); }

struct Xform {
    float r0x, r0y, r0z;  // approach
    float r1x, r1y, r1z;  // axis_y
    float r2x, r2y, r2z;  // minor
    float cx, cy, cz;     // center
};

// Replicates _transform()'s per-batch math in exact f32 op order (no fma
// contraction, correctly-rounded div/sqrt, f64->f32 cos/sin).
__device__ Xform compute_xform(const float* __restrict__ gr) {
    Xform X;
    X.cx = gr[0]; X.cy = gr[1]; X.cz = gr[2];
    float vx = gr[3], vy = gr[4], vz = gr[5];
    float angle = gr[6];
    float c = (float)cos((double)angle);
    float s = (float)sin((double)angle);

    // axis_y = normalize_fix(v, [0,1,0]); eps = 1e-12
    float n  = __fsqrt_rn(fa(fa(fm(vx, vx), fm(vy, vy)), fm(vz, vz)));
    float dn = fa(n, 1e-12f);
    float ayx = fd(vx, dn), ayy = fd(vy, dn), ayz = fd(vz, dn);
    if (n == 0.0f) { ayx = 0.0f; ayy = 1.0f; ayz = 0.0f; }

    // axis_x = normalize_fix([ay.y, -ay.x, 0], [1,0,0])
    float bx = ayy, by = -ayx, bz = 0.0f;
    float n2  = __fsqrt_rn(fa(fa(fm(bx, bx), fm(by, by)), fm(bz, bz)));
    float dn2 = fa(n2, 1e-12f);
    float axx = fd(bx, dn2), axy = fd(by, dn2), axz = fd(bz, dn2);
    if (n2 == 0.0f) { axx = 1.0f; axy = 0.0f; axz = 0.0f; }

    // axis_z = cross(axis_x, axis_y); / where(nz==0,1,nz); fallback [0,0,1]
    float zx = fs(fm(axy, ayz), fm(axz, ayy));
    float zy = fs(fm(axz, ayx), fm(axx, ayz));
    float zz = fs(fm(axx, ayy), fm(axy, ayx));
    float nz = __fsqrt_rn(fa(fa(fm(zx, zx), fm(zy, zy)), fm(zz, zz)));
    float dz = (nz == 0.0f) ? 1.0f : nz;
    zx = fd(zx, dz); zy = fd(zy, dz); zz = fd(zz, dz);
    if (nz == 0.0f) { zx = 0.0f; zy = 0.0f; zz = 1.0f; }

    // approach = normalize_fix(M[:, :, 0], [1,0,0]);
    // M[:,0] = (axis_x*c + axis_y*0) + axis_z*s; the +0 term is exact.
    float px = fa(fm(axx, c), fm(zx, s));
    float py = fa(fm(axy, c), fm(zy, s));
    float pz = fa(fm(axz, c), fm(zz, s));
    float n3  = __fsqrt_rn(fa(fa(fm(px, px), fm(py, py)), fm(pz, pz)));
    float dn3 = fa(n3, 1e-12f);
    float apx = fd(px, dn3), apy = fd(py, dn3), apz = fd(pz, dn3);
    if (n3 == 0.0f) { apx = 1.0f; apy = 0.0f; apz = 0.0f; }

    // minor = cross(approach, axis_y)   (not normalized)
    float mx = fs(fm(apy, ayz), fm(apz, ayy));
    float my = fs(fm(apz, ayx), fm(apx, ayz));
    float mz = fs(fm(apx, ayy), fm(apy, ayx));

    X.r0x = apx; X.r0y = apy; X.r0z = apz;
    X.r1x = ayx; X.r1y = ayy; X.r1z = ayz;
    X.r2x = mx;  X.r2y = my;  X.r2z = mz;
    return X;
}

__device__ __forceinline__ void transform_point(const Xform& X,
                                                float px, float py, float pz,
                                                float& x, float& y, float& z) {
    float dx = fs(px, X.cx), dy = fs(py, X.cy), dz = fs(pz, X.cz);
    // ((m0*d0 + m1*d1) + m2*d2) -- matches einsum/np sequential dot order
    x = fa(fa(fm(X.r0x, dx), fm(X.r0y, dy)), fm(X.r0z, dz));
    y = fa(fa(fm(X.r1x, dx), fm(X.r1y, dy)), fm(X.r1z, dz));
    z = fa(fa(fm(X.r2x, dx), fm(X.r2y, dy)), fm(X.r2z, dz));
}

#define NTHREADS 1024
#define NWAVES (NTHREADS / 64)

extern "C" __global__ void __launch_bounds__(NTHREADS)
gripper_kernel(const float* __restrict__ gp,    // (B,G,6)
               const int*   __restrict__ gidx,  // (B,G)
               const float* __restrict__ grasp, // (B,7)
               const float* __restrict__ widths_p,
               const float* __restrict__ height_p,
               const float* __restrict__ depths_p,
               float* __restrict__ out,
               int B, int G, int RN) {
    const int b    = blockIdx.x;
    const int tid  = threadIdx.x;
    const int lane = tid & 63;
    const int wave = tid >> 6;

    extern __shared__ int s_idx[];          // RN entries
    __shared__ int s_cnt[NWAVES];
    __shared__ int s_total;

    const Xform X = compute_xform(grasp + (size_t)b * 7);

    const float x_lim = fm(*depths_p, 0.5f);  // depths/2 (exact /2)
    const float y_lim = fm(*widths_p, 0.5f);
    const float z_lim = fm(*height_p, 0.5f);

    if (tid == 0) s_total = 0;
    __syncthreads();

    const float* __restrict__ gpb = gp + (size_t)b * G * 6;

    // ---- Phase B: ordered compaction of masked indices into s_idx ----
    for (int base = 0; base < G; base += NTHREADS) {
        int g = base + tid;
        const float* p = gpb + (size_t)g * 6;
        float x, y, z;
        transform_point(X, p[0], p[1], p[2], x, y, z);
        bool m = (x > 0.0f) & (x < x_lim) & (y > -y_lim) & (y < y_lim) &
                 (z > -z_lim) & (z < z_lim);

        unsigned long long bal = __ballot(m);
        if (lane == 0) s_cnt[wave] = __popcll(bal);
        __syncthreads();

        int off = s_total;
        #pragma unroll
        for (int w = 0; w < NWAVES; ++w)
            if (w < wave) off += s_cnt[w];
        int pos = off + __popcll(bal & ((1ull << lane) - 1ull));
        if (m && pos < RN) s_idx[pos] = g;
        __syncthreads();

        if (tid == 0) {
            int t = 0;
            #pragma unroll
            for (int w = 0; w < NWAVES; ++w) t += s_cnt[w];
            s_total += t;
        }
        __syncthreads();
    }

    const int count = s_total;

    // ---- Phase C: emit outputs ----
    float* __restrict__ out0 = out;                               // (B,RN,6)
    float* __restrict__ out1 = out + (size_t)B * RN * 6;          // (B,RN)
    float* __restrict__ out2 = out1 + (size_t)B * RN;             // (B,RN)
    float* __restrict__ out3 = out2 + (size_t)B * RN;             // (B)

    if (count > 5) {
        const int m = count < RN ? count : RN;  // j%count == j%m for j<RN
        for (int j = tid; j < RN; j += NTHREADS) {
            int i = s_idx[j % m];
            const float* p = gpb + (size_t)i * 6;
            float x, y, z;
            transform_point(X, p[0], p[1], p[2], x, y, z);
            size_t o0 = ((size_t)b * RN + j) * 6;
            out0[o0 + 0] = x;
            out0[o0 + 1] = y;
            out0[o0 + 2] = z;
            out0[o0 + 3] = p[3];
            out0[o0 + 4] = p[4];
            out0[o0 + 5] = p[5];
            out1[(size_t)b * RN + j] = (float)i;
            out2[(size_t)b * RN + j] = (float)gidx[(size_t)b * G + i];
        }
        if (tid == 0) out3[b] = 1.0f;
    } else {
        for (int j = tid; j < RN; j += NTHREADS) {
            size_t o0 = ((size_t)b * RN + j) * 6;
            #pragma unroll
            for (int k = 0; k < 6; ++k) out0[o0 + k] = -1.0f;
            out1[(size_t)b * RN + j] = -1.0f;
            out2[(size_t)b * RN + j] = -1.0f;
        }
        if (tid == 0) out3[b] = 0.0f;
    }
}

extern "C" void kernel_launch(void* const* d_in, const int* in_sizes, int n_in,
                              void* d_out, int out_size, void* d_ws, size_t ws_size,
                              hipStream_t stream) {
    const float* gp     = (const float*)d_in[0];
    const int*   gidx   = (const int*)d_in[1];
    const float* grasp  = (const float*)d_in[2];
    const float* widths = (const float*)d_in[3];
    const float* height = (const float*)d_in[4];
    const float* depths = (const float*)d_in[5];
    float* out = (float*)d_out;

    const int B  = in_sizes[2] / 7;
    const int G  = in_sizes[1] / B;
    // out_size = B*(8*RN + 1)  ->  RN
    const int RN = (out_size / B - 1) / 8;

    const size_t smem = (size_t)RN * sizeof(int);
    gripper_kernel<<<B, NTHREADS, smem, stream>>>(gp, gidx, grasp, widths,
                                                  height, depths, out, B, G, RN);
}